// Round 11
// baseline (251.168 us; speedup 1.0000x reference)
//
#include <hip/hip_runtime.h>
#include <cstdint>
#include <cstddef>

// Problem constants (fixed by reference).
#define BATCH 16
#define SEQ   4096
#define NS    512
#define TLAG  96             // truncation (r10-verified): y error ~2e-3 << bf16 noise
#define CTILE 128            // conv time-tile rows per block (r6/r10 best config)
#define XROWS (CTILE + TLAG - 1)   // 223 staged rows
#define XSTR  72             // LDS row stride in u16 (144 B)
#define BLK   32768          // one 64x512 row-block in u16 (64*512)
#define NB    128            // chain grid size (barrier count)
#define FSTR  65             // f32 reduce-buffer row stride (bank-spread)

typedef unsigned short u16;
typedef unsigned int   u32;
typedef unsigned long long u64;
typedef short bf16x8 __attribute__((ext_vector_type(8)));   // 8 bf16 = 4 VGPRs
typedef float f32x4  __attribute__((ext_vector_type(4)));   // MFMA accumulator

__device__ __forceinline__ u16 f2bf(float f) {
    u32 u = __builtin_bit_cast(u32, f);
    return (u16)((u + 0x7FFFu + ((u >> 16) & 1u)) >> 16);   // RNE
}
__device__ __forceinline__ float bf2f(u16 h) {
    return __builtin_bit_cast(float, (u32)h << 16);
}

// Write-through 8B store (relaxed agent atomic -> coherent point). r3/r9
// proven. Used ONLY for buffers consumed in-kernel; Gsw (consumed by the
// next kernel) uses plain cached stores (kernel-boundary coherence).
__device__ __forceinline__ void wt_store(u16* p, ushort4 v) {
    __hip_atomic_store((u64*)p, __builtin_bit_cast(u64, v),
                       __ATOMIC_RELAXED, __HIP_MEMORY_SCOPE_AGENT);
}

// Fence-free grid barrier with watchdog (r9-verified on hardware).
__device__ __forceinline__ void gbar(u32* __restrict__ f)
{
    __syncthreads();
    if (threadIdx.x == 0) {
        __hip_atomic_fetch_add(f, 1u, __ATOMIC_RELAXED, __HIP_MEMORY_SCOPE_AGENT);
        u32 it = 0;
        while (__hip_atomic_load(f, __ATOMIC_RELAXED, __HIP_MEMORY_SCOPE_AGENT) < (u32)NB) {
            __builtin_amdgcn_s_sleep(8);
            if (++it > 2000000u) break;           // ~0.4 s watchdog
        }
    }
    __syncthreads();
}

// ---------------------------------------------------------------------------
// gemm_core512: split-K 64x64x512 tile on 512 threads (8 waves). Wave w8:
// kh = w8>>2 owns K-half kh*256..+256; wq = w8&3 owns rows wq*16..+16.
// All 8 A-frags preloaded -> ~10x more lines in flight than the r9 unroll-4
// core (the measured fused-phase bottleneck: ~20 lines/block at L3 latency).
// f32 LDS reduce (stride-65, bank-spread) leaves the full-K acc in waves
// kh==0 (= tids 0..255). Association differs from r4 core -> absmax drifts
// slightly (pre-registered, accept <= ~0.1).
// ---------------------------------------------------------------------------
__device__ __forceinline__ void gemm_core512(const u16* __restrict__ apM,
                                             const u16* __restrict__ bT, int n0,
                                             float* __restrict__ ldsF,
                                             f32x4 acc[4])
{
    const int tid = threadIdx.x;
    const int w8 = tid >> 6, kh = w8 >> 2, wq = w8 & 3;
    const int l = tid & 63, lr = l & 15, q8 = (l >> 4) * 8;

    const u16* ap  = apM + (size_t)(wq * 16 + lr) * NS + kh * 256 + q8;
    const u16* bp0 = bT  + (size_t)(n0 + lr) * NS + kh * 256 + q8;

    const f32x4 zero = {0.f, 0.f, 0.f, 0.f};
    #pragma unroll
    for (int nt = 0; nt < 4; ++nt) acc[nt] = zero;

    bf16x8 af[8];
    #pragma unroll
    for (int ks = 0; ks < 8; ++ks) af[ks] = *(const bf16x8*)(ap + ks * 32);

    #pragma unroll
    for (int ks = 0; ks < 8; ++ks) {
        #pragma unroll
        for (int nt = 0; nt < 4; ++nt) {
            const bf16x8 bfr = *(const bf16x8*)(bp0 + (size_t)nt * 16 * NS + ks * 32);
            acc[nt] = __builtin_amdgcn_mfma_f32_16x16x32_bf16(af[ks], bfr, acc[nt], 0, 0, 0);
        }
    }

    // reduce K-halves: kh==1 writes partials, kh==0 adds.
    const int rr = (l >> 4) * 4;
    __syncthreads();   // guard ldsF reuse across sequential tiles
    if (kh == 1) {
        #pragma unroll
        for (int nt = 0; nt < 4; ++nt)
            #pragma unroll
            for (int r = 0; r < 4; ++r)
                ldsF[(wq * 16 + rr + r) * FSTR + nt * 16 + lr] = acc[nt][r];
    }
    __syncthreads();
    if (kh == 0) {
        #pragma unroll
        for (int nt = 0; nt < 4; ++nt)
            #pragma unroll
            for (int r = 0; r < 4; ++r)
                acc[nt][r] += ldsF[(wq * 16 + rr + r) * FSTR + nt * 16 + lr];
    }
}

// ---------------------------------------------------------------------------
// gemm_wt512: core + r9-verified contiguous-wt epilogues (oT direct from
// waves 0-3; oRM via u16 LDS bounce read by tids 0..255).
// ---------------------------------------------------------------------------
__device__ __forceinline__ void gemm_wt512(const u16* __restrict__ apM,
                                           const u16* __restrict__ bT, int n0,
                                           u16* __restrict__ oRM,
                                           u16* __restrict__ oT, int rowT,
                                           u16* __restrict__ ldsU,
                                           float* __restrict__ ldsF)
{
    const int tid = threadIdx.x;
    const int w8 = tid >> 6, kh = w8 >> 2, wq = w8 & 3;
    const int l = tid & 63, lr = l & 15;
    const int rr = (l >> 4) * 4;

    f32x4 acc[4];
    gemm_core512(apM, bT, n0, ldsF, acc);

    if (oT && kh == 0) {
        #pragma unroll
        for (int nt = 0; nt < 4; ++nt) {
            const int col = n0 + nt * 16 + lr;
            ushort4 pk;
            pk.x = f2bf(acc[nt][0]); pk.y = f2bf(acc[nt][1]);
            pk.z = f2bf(acc[nt][2]); pk.w = f2bf(acc[nt][3]);
            wt_store(oT + (size_t)col * NS + rowT + wq * 16 + rr, pk);
        }
    }
    if (oRM) {
        __syncthreads();
        if (kh == 0) {
            #pragma unroll
            for (int nt = 0; nt < 4; ++nt)
                #pragma unroll
                for (int r = 0; r < 4; ++r)
                    ldsU[(wq * 16 + rr + r) * 72 + nt * 16 + lr] = f2bf(acc[nt][r]);
        }
        __syncthreads();
        if (tid < 256) {
            const int r  = tid >> 2;             // 0..63
            const int c0 = (tid & 3) * 16;       // 0,16,32,48
            #pragma unroll
            for (int k = 0; k < 4; ++k)
                wt_store(oRM + (size_t)r * NS + n0 + c0 + k * 4,
                         *(const ushort4*)&ldsU[r * 72 + c0 + k * 4]);
        }
    }
}

// ---------------------------------------------------------------------------
// g_tile512: core + r4/r10-verified G epilogue (bounce lds[o][i], B-fragment
// swizzle read, D fold at m==0). Gsw stores are PLAIN cached (consumed only
// by the next kernel -> kernel-boundary coherence; avoids r9's conv L3
// first-touch penalty).
// ---------------------------------------------------------------------------
__device__ __forceinline__ void g_tile512(const u16* __restrict__ ap0,
                                          const u16* __restrict__ bT0, int m,
                                          const float* __restrict__ D,
                                          u16* __restrict__ Gsw,
                                          u16* __restrict__ ldsU,
                                          float* __restrict__ ldsF)
{
    const int tid = threadIdx.x;
    const int w8 = tid >> 6, kh = w8 >> 2, wq = w8 & 3;
    const int l = tid & 63, lr = l & 15;
    const int rr = (l >> 4) * 4;

    f32x4 acc[4];
    gemm_core512(ap0, bT0, 0, ldsF, acc);

    __syncthreads();
    if (kh == 0) {       // ldsU[o][i] = f2bf(G_m[o][i]); i = wq*16+rr+rk, o = nt*16+lr
        #pragma unroll
        for (int nt = 0; nt < 4; ++nt)
            #pragma unroll
            for (int rk = 0; rk < 4; ++rk)
                ldsU[(nt * 16 + lr) * 72 + (wq * 16 + rr + rk)] = f2bf(acc[nt][rk]);
    }
    __syncthreads();

    if (tid < 256) {
        const int f = tid >> 6;              // 0..3
        #pragma unroll
        for (int f2 = 0; f2 < 8; f2 += 4) {  // fragments f and f+4
            const int fi = f2 + f;
            const int ks = fi >> 2, nt = fi & 3;
            const int o  = nt * 16 + (l & 15);
            const int i0 = ks * 32 + (l >> 4) * 8;
            u16 v[8];
            #pragma unroll
            for (int j = 0; j < 8; ++j) {
                u16 gv = ldsU[o * 72 + i0 + j];
                if (m == 0) gv = f2bf(bf2f(gv) + D[o * 64 + i0 + j]);
                v[j] = gv;
            }
            u16* dst = Gsw + ((size_t)(m * 8 + fi) * 64 + l) * 8;
            *(ushort4*)(dst + 0) = *(const ushort4*)&v[0];
            *(ushort4*)(dst + 4) = *(const ushort4*)&v[4];
        }
    }
}

// ---------------------------------------------------------------------------
// chain9: ONE launch for the entire setup chain. 128 blocks x 512 threads;
// 8 fence-free barriers. Coherence (r9-verified on HW): in-kernel data
// written once via contiguous wt_store, read plain-cached only after its
// level barrier; fresh-buffer discipline; launch-time cache invalidate
// kills stale lines across graph replays.
// ---------------------------------------------------------------------------
__global__ __launch_bounds__(512, 1) void chain9(const float* __restrict__ A,
                                                 const float* __restrict__ B,
                                                 const float* __restrict__ C,
                                                 const float* __restrict__ D,
                                                 u16* __restrict__ Arm,
                                                 u16* __restrict__ At,
                                                 u16* __restrict__ A2rm,
                                                 u16* __restrict__ A2t,
                                                 u16* __restrict__ A4rm,
                                                 u16* __restrict__ A4t,
                                                 u16* __restrict__ A8rm,
                                                 u16* __restrict__ A8t,
                                                 u16* __restrict__ A16rm,
                                                 u16* __restrict__ A16t,
                                                 u16* __restrict__ A32rm,
                                                 u16* __restrict__ A32t,
                                                 u16* __restrict__ A64rm,
                                                 u16* __restrict__ L,
                                                 u16* __restrict__ Rt,
                                                 u16* __restrict__ Gsw,
                                                 u32* __restrict__ flg)
{
    __shared__ u16   ldsU[64 * 72];      //  9,216 B bounce
    __shared__ float ldsF[64 * FSTR];    // 16,640 B split-K reduce
    const int tid = threadIdx.x;
    const int bid = blockIdx.x;
    const int gid = bid * 512 + tid;     // 0..65535

    // ---- level 0: prep (A -> Arm/At, B -> Rt0 = B^T, C -> L0) ----
    {
        u16 v[4];
        {   // Arm: 4 contiguous elems per thread
            const int base = gid * 4;
            #pragma unroll
            for (int i = 0; i < 4; ++i) v[i] = f2bf(A[base + i]);
            wt_store(Arm + base, *(const ushort4*)v);
        }
        {   // At: col = gid>>7, rows r0..r0+3
            const int col = gid >> 7, r0 = (gid & 127) * 4;
            #pragma unroll
            for (int i = 0; i < 4; ++i) v[i] = f2bf(A[(size_t)(r0 + i) * 512 + col]);
            wt_store(At + (size_t)col * 512 + r0, *(const ushort4*)v);
        }
        if (gid < 8192) {   // Rt0[c][k] = B[k][c]
            const int col = gid >> 7, k0 = (gid & 127) * 4;
            #pragma unroll
            for (int i = 0; i < 4; ++i) v[i] = f2bf(B[(size_t)(k0 + i) * 64 + col]);
            wt_store(Rt + (size_t)col * 512 + k0, *(const ushort4*)v);
        }
        if (gid < 16384) {  // L0 = f2bf(C), contiguous
            const int base = gid * 4;
            #pragma unroll
            for (int i = 0; i < 4; ++i) v[i] = f2bf(C[base + i]);
            wt_store(L + base, *(const ushort4*)v);
        }
    }
    gbar(flg + 0);

    // ---- levels 1..4: A^{2h} = A^h * A^h (rm+t) ; L[h+j] = L[j] * A^h ----
    {
        const u16* sqI[4] = {Arm, A2rm, A4rm, A8rm};
        const u16* sqT[4] = {At,  A2t,  A4t,  A8t};
        u16* sqOR[4] = {A2rm, A4rm, A8rm, A16rm};
        u16* sqOT[4] = {A2t,  A4t,  A8t,  A16t};
        #pragma unroll 1
        for (int lvl = 0; lvl < 4; ++lvl) {
            const int h   = 1 << lvl;
            const int tot = 64 + 8 * h;
            for (int t = bid; t < tot; t += NB) {
                if (t < 64) {
                    const int mr = t >> 3, n0 = (t & 7) * 64;
                    gemm_wt512(sqI[lvl] + (size_t)mr * BLK, sqT[lvl], n0,
                               sqOR[lvl] + (size_t)mr * BLK, sqOT[lvl], mr * 64,
                               ldsU, ldsF);
                } else {
                    const int tt = t - 64, j = tt >> 3, n0 = (tt & 7) * 64;
                    gemm_wt512(L + (size_t)j * BLK, sqT[lvl], n0,
                               L + (size_t)(h + j) * BLK, nullptr, 0, ldsU, ldsF);
                }
            }
            gbar(flg + 1 + lvl);
        }
    }

    // ---- level 5: A32 = A16*A16 (rm+t) ; Rt[1] = Rt[0] x A16rm ----
    for (int t = bid; t < 64 + 8; t += NB) {
        if (t < 64) {
            const int mr = t >> 3, n0 = (t & 7) * 64;
            gemm_wt512(A16rm + (size_t)mr * BLK, A16t, n0,
                       A32rm + (size_t)mr * BLK, A32t, mr * 64, ldsU, ldsF);
        } else {
            const int n0 = ((t - 64) & 7) * 64;
            gemm_wt512(Rt, A16rm, n0, Rt + 1 * BLK, nullptr, 0, ldsU, ldsF);
        }
    }
    gbar(flg + 5);

    // ---- level 6: A64 = A32*A32 (rm only) ; Rt[2+j] = Rt[j] x A32rm ----
    for (int t = bid; t < 64 + 16; t += NB) {
        if (t < 64) {
            const int mr = t >> 3, n0 = (t & 7) * 64;
            gemm_wt512(A32rm + (size_t)mr * BLK, A32t, n0,
                       A64rm + (size_t)mr * BLK, nullptr, 0, ldsU, ldsF);
        } else {
            const int tt = t - 64, j = tt >> 3, n0 = (tt & 7) * 64;
            gemm_wt512(Rt + (size_t)j * BLK, A32rm, n0,
                       Rt + (size_t)(2 + j) * BLK, nullptr, 0, ldsU, ldsF);
        }
    }
    gbar(flg + 6);

    // ---- level 7: Rt[4+j] = Rt[j] x A64rm, j<2 (q = 4,5 at TLAG=96) ----
    for (int t = bid; t < 16; t += NB) {
        const int j = t >> 3, n0 = (t & 7) * 64;
        gemm_wt512(Rt + (size_t)j * BLK, A64rm, n0,
                   Rt + (size_t)(4 + j) * BLK, nullptr, 0, ldsU, ldsF);
    }
    gbar(flg + 7);

    // ---- level 8: G_m = L_r R_q (swizzled + D fold), 96 tiles ----
    for (int m = bid; m < TLAG; m += NB) {
        g_tile512(Rt + (size_t)(m >> 4) * BLK, L + (size_t)(m & 15) * BLK,
                  m, D, Gsw, ldsU, ldsF);
    }
    // no barrier: Gsw consumed by the next kernel (boundary release).
}

// ---------------------------------------------------------------------------
// conv_kernel: EXACT r10 version (verified 61.5us, MfmaUtil 33%, TLAG=96).
// ---------------------------------------------------------------------------
__global__ __launch_bounds__(256, 2) void conv_kernel(const float* __restrict__ x,
                                                      const u16* __restrict__ gsw,
                                                      float* __restrict__ y)
{
    __shared__ u16 Xs[XROWS * XSTR];   // 223*72*2 = 32,112 B
    __shared__ uint4 Gs[2][1024];      // 32,768 B

    const int tid = threadIdx.x;
    const int b  = blockIdx.y;
    const int t0 = blockIdx.x * CTILE;

    {
        const int g = tid & 15;
        int r = tid >> 4;                    // 0..15
        #pragma unroll
        for (int it = 0; it < 14; ++it, r += 16) {
            if (r < XROWS) {
                const int t = t0 + r - (TLAG - 1);
                ushort4 o;
                if (t < 0) {
                    o.x = 0; o.y = 0; o.z = 0; o.w = 0;
                } else {
                    const float4 v = *(const float4*)(x + ((size_t)b * SEQ + t) * 64 + g * 4);
                    o.x = f2bf(v.x); o.y = f2bf(v.y); o.z = f2bf(v.z); o.w = f2bf(v.w);
                }
                *(ushort4*)&Xs[r * XSTR + g * 4] = o;
            }
        }
    }

    const uint4* gp4 = (const uint4*)gsw;
    uint4 st[4];
    #pragma unroll
    for (int j = 0; j < 4; ++j) st[j] = gp4[tid + j * 256];   // pair 0

    const int w    = tid >> 6;
    const int l    = tid & 63;
    const int lr   = l & 15;
    const int q8   = (l >> 4) * 8;
    const int wrow = w * 32;

    f32x4 acc[2][4];
    const f32x4 zero = {0.f, 0.f, 0.f, 0.f};
    #pragma unroll
    for (int mt = 0; mt < 2; ++mt)
        #pragma unroll
        for (int nt = 0; nt < 4; ++nt) acc[mt][nt] = zero;

    #pragma unroll
    for (int j = 0; j < 4; ++j) Gs[0][tid + j * 256] = st[j];
    __syncthreads();

    for (int p = 0; p < TLAG / 2; ++p) {      // pair of lags {2p, 2p+1}
        const int cur = p & 1;
        if (p < TLAG / 2 - 1) {
            #pragma unroll
            for (int j = 0; j < 4; ++j) st[j] = gp4[(p + 1) * 1024 + tid + j * 256];
        }
        #pragma unroll
        for (int sub = 0; sub < 2; ++sub) {
            const int m = 2 * p + sub;
            bf16x8 bc[8];
            #pragma unroll
            for (int f = 0; f < 8; ++f)
                bc[f] = __builtin_bit_cast(bf16x8, Gs[cur][sub * 512 + f * 64 + l]);

            const int rbase = wrow + lr + (TLAG - 1) - m;
            bf16x8 a[2][2];
            #pragma unroll
            for (int mt = 0; mt < 2; ++mt)
                #pragma unroll
                for (int ks = 0; ks < 2; ++ks)
                    a[mt][ks] = *(const bf16x8*)&Xs[(rbase + mt * 16) * XSTR + ks * 32 + q8];

            #pragma unroll
            for (int ks = 0; ks < 2; ++ks)
                #pragma unroll
                for (int mt = 0; mt < 2; ++mt)
                    #pragma unroll
                    for (int nt = 0; nt < 4; ++nt)
                        acc[mt][nt] = __builtin_amdgcn_mfma_f32_16x16x32_bf16(
                            a[mt][ks], bc[ks * 4 + nt], acc[mt][nt], 0, 0, 0);
        }
        if (p < TLAG / 2 - 1) {
            #pragma unroll
            for (int j = 0; j < 4; ++j) Gs[cur ^ 1][tid + j * 256] = st[j];
        }
        __syncthreads();
    }

    const int rr = (l >> 4) * 4;
    #pragma unroll
    for (int mt = 0; mt < 2; ++mt) {
        #pragma unroll
        for (int nt = 0; nt < 4; ++nt) {
            const int t = t0 + wrow + mt * 16 + rr;
            const int o = nt * 16 + lr;
            float* yp = y + ((size_t)b * SEQ + t) * 64 + o;
            #pragma unroll
            for (int r = 0; r < 4; ++r) yp[(size_t)r * 64] = acc[mt][nt][r];
        }
    }
}

// ---------------------------------------------------------------------------
// Workspace layout (bytes, 16-aligned) — r10 offsets kept:
//   8,650,752   Arm .. 14,942,208 A64rm   (13 x 512KB power buffers)
//  15,532,032   L       1,048,576
//  16,580,608   Rt        524,288
//  17,104,896   Gsw       786,432   (96 lags)
//  17,891,328   flg            64   (8 u32 barrier counters, memset each run)
//  total: 17,891,392
// ---------------------------------------------------------------------------
extern "C" void kernel_launch(void* const* d_in, const int* in_sizes, int n_in,
                              void* d_out, int out_size, void* d_ws, size_t ws_size,
                              hipStream_t stream)
{
    const float* x = (const float*)d_in[0];
    const float* A = (const float*)d_in[1];
    const float* B = (const float*)d_in[2];
    const float* C = (const float*)d_in[3];
    const float* D = (const float*)d_in[4];
    float* y = (float*)d_out;

    char* w = (char*)d_ws;
    u16* Arm   = (u16*)(w + 8650752);
    u16* At    = (u16*)(w + 9175040);
    u16* A2rm  = (u16*)(w + 9699328);
    u16* A2t   = (u16*)(w + 10223616);
    u16* A4rm  = (u16*)(w + 10747904);
    u16* A4t   = (u16*)(w + 11272192);
    u16* A8rm  = (u16*)(w + 11796480);
    u16* A8t   = (u16*)(w + 12320768);
    u16* A16rm = (u16*)(w + 12845056);
    u16* A16t  = (u16*)(w + 13369344);
    u16* A32rm = (u16*)(w + 13893632);
    u16* A32t  = (u16*)(w + 14417920);
    u16* A64rm = (u16*)(w + 14942208);
    u16* L     = (u16*)(w + 15532032);
    u16* Rt    = (u16*)(w + 16580608);
    u16* Gsw   = (u16*)(w + 17104896);
    u32* flg   = (u32*)(w + 17891328);

    hipMemsetAsync(flg, 0, 64, stream);   // replay-safe barrier counters

    chain9<<<NB, 512, 0, stream>>>(A, B, C, D,
                                   Arm, At, A2rm, A2t, A4rm, A4t, A8rm, A8t,
                                   A16rm, A16t, A32rm, A32t, A64rm,
                                   L, Rt, Gsw, flg);

    conv_kernel<<<dim3(SEQ / CTILE, BATCH), 256, 0, stream>>>(x, Gsw, y);
}

// Round 12
// 210.157 us; speedup vs baseline: 1.1951x; 1.1951x over previous
//
#include <hip/hip_runtime.h>
#include <cstdint>
#include <cstddef>

// Problem constants (fixed by reference).
#define BATCH 16
#define SEQ   4096
#define NS    512
#define TLAG  96             // truncation (r10-verified): y error ~2e-3 << bf16 noise
#define CTILE 128            // conv time-tile rows per block
#define XROWS (CTILE + TLAG - 1)   // 223 staged rows
#define XSTR  72             // LDS row stride in u16 (144 B)
#define BLK   32768          // one 64x512 row-block in u16 (64*512)
#define RSTR  66             // f32 reduce-buffer row stride (bank-spread)

typedef unsigned short u16;
typedef unsigned int   u32;
typedef short bf16x8 __attribute__((ext_vector_type(8)));   // 8 bf16 = 4 VGPRs
typedef float f32x4  __attribute__((ext_vector_type(4)));   // MFMA accumulator

__device__ __forceinline__ u16 f2bf(float f) {
    u32 u = __builtin_bit_cast(u32, f);
    return (u16)((u + 0x7FFFu + ((u >> 16) & 1u)) >> 16);   // RNE
}
__device__ __forceinline__ float bf2f(u16 h) {
    return __builtin_bit_cast(float, (u32)h << 16);
}

// ---------------------------------------------------------------------------
// prep_mat: matrix-only input conversion (r7/r10-verified).
//  A -> Arm + At; B -> Rt[0] (= B^T); C -> L[0]. 1280 blocks x 256.
// ---------------------------------------------------------------------------
__global__ __launch_bounds__(256) void prep_mat(const float* __restrict__ A,
                                                const float* __restrict__ B,
                                                const float* __restrict__ C,
                                                u16* __restrict__ Arm,
                                                u16* __restrict__ At,
                                                u16* __restrict__ Rt,
                                                u16* __restrict__ L)
{
    const int id = blockIdx.x * 256 + threadIdx.x;
    if (id < 262144) {                                 // A: 512x512
        const int c = id & 511;
        const u16 v = f2bf(A[id]);
        Arm[id] = v;
        At[(size_t)c * 512 + (id >> 9)] = v;
    } else if (id < 262144 + 32768) {                  // B: 512x64 -> B^T (=R_0^T)
        const int i = id - 262144;
        Rt[(size_t)(i & 63) * 512 + (i >> 6)] = f2bf(B[i]);
    } else {                                           // C: 64x512 -> L_0
        const int i = id - 262144 - 32768;             // < 65536
        L[i] = f2bf(C[i]);
    }
}

// ---------------------------------------------------------------------------
// gemm_tile: one 64(M)x64(N) output tile, K=512 (r0-r10 verified core).
// ---------------------------------------------------------------------------
__device__ __forceinline__ void gemm_tile(const u16* __restrict__ apM,
                                          const u16* __restrict__ bT, int n0,
                                          u16* __restrict__ oRM,
                                          u16* __restrict__ oT, int rowT,
                                          u16* __restrict__ lds)
{
    const int tid = threadIdx.x;
    const int w = tid >> 6, l = tid & 63;
    const int lr = l & 15, q8 = (l >> 4) * 8;

    const u16* ap  = apM + (size_t)(w * 16 + lr) * NS + q8;
    const u16* bp0 = bT  + (size_t)(n0 + lr) * NS + q8;

    f32x4 acc[4];
    const f32x4 zero = {0.f, 0.f, 0.f, 0.f};
    #pragma unroll
    for (int nt = 0; nt < 4; ++nt) acc[nt] = zero;

    #pragma unroll 4
    for (int ks = 0; ks < 16; ++ks) {
        const bf16x8 a = *(const bf16x8*)(ap + ks * 32);
        #pragma unroll
        for (int nt = 0; nt < 4; ++nt) {
            const bf16x8 bfr = *(const bf16x8*)(bp0 + (size_t)nt * 16 * NS + ks * 32);
            acc[nt] = __builtin_amdgcn_mfma_f32_16x16x32_bf16(a, bfr, acc[nt], 0, 0, 0);
        }
    }

    const int rr = (l >> 4) * 4;    // C/D: row = (lane>>4)*4 + reg, col = lane&15
    if (oT) {
        #pragma unroll
        for (int nt = 0; nt < 4; ++nt) {
            const int col = n0 + nt * 16 + lr;
            ushort4 pk;
            pk.x = f2bf(acc[nt][0]); pk.y = f2bf(acc[nt][1]);
            pk.z = f2bf(acc[nt][2]); pk.w = f2bf(acc[nt][3]);
            *(ushort4*)(oT + (size_t)col * NS + rowT + w * 16 + rr) = pk;
        }
    }
    if (oRM) {
        #pragma unroll
        for (int nt = 0; nt < 4; ++nt)
            #pragma unroll
            for (int r = 0; r < 4; ++r)
                lds[(w * 16 + rr + r) * 72 + nt * 16 + lr] = f2bf(acc[nt][r]);
        __syncthreads();
        const int r  = tid >> 2;             // 0..63
        const int c0 = (tid & 3) * 16;       // 0,16,32,48
        #pragma unroll
        for (int k = 0; k < 4; ++k) {
            const ushort4 q = *(const ushort4*)&lds[r * 72 + c0 + k * 4];
            *(ushort4*)(oRM + (size_t)r * NS + n0 + c0 + k * 4) = q;
        }
    }
}

// ---------------------------------------------------------------------------
// stage_kernel: one doubling stage (r4/r10 verified).
// ---------------------------------------------------------------------------
__global__ __launch_bounds__(256, 1) void stage_kernel(const u16* __restrict__ expAp,
                                                       const u16* __restrict__ expBT,
                                                       u16* __restrict__ expOut,
                                                       const u16* __restrict__ sqIn,
                                                       const u16* __restrict__ sqInT,
                                                       u16* __restrict__ sqOutRM,
                                                       u16* __restrict__ sqOutT,
                                                       int E)
{
    __shared__ u16 lds[64 * 72];   // 9,216 B bounce buffer
    const int t = blockIdx.x;
    if (t < E) {
        const int j = t >> 3, n0 = (t & 7) * 64;
        gemm_tile(expAp + (size_t)j * BLK, expBT, n0,
                  expOut + (size_t)j * BLK, nullptr, 0, lds);
    } else {
        const int tt = t - E;
        const int mr = tt >> 3, n0 = (tt & 7) * 64;
        gemm_tile(sqIn + (size_t)mr * BLK, sqInT, n0,
                  sqOutRM + (size_t)mr * BLK, sqOutT, mr * 64, lds);
    }
}

// ---------------------------------------------------------------------------
// g_kernel: G_m via G^T = R_q^T x L_r (r4/r10 verified). grid = 96 blocks.
// ---------------------------------------------------------------------------
__global__ __launch_bounds__(256, 1) void g_kernel(const u16* __restrict__ Rt,
                                                   const u16* __restrict__ L,
                                                   const float* __restrict__ D,
                                                   u16* __restrict__ Gsw)
{
    __shared__ u16 lds[64 * 72];
    const int m = blockIdx.x;
    const int q = m >> 4, r = m & 15;
    const u16* ap0 = Rt + (size_t)q * BLK;
    const u16* bT0 = L  + (size_t)r * BLK;

    const int tid = threadIdx.x;
    const int w = tid >> 6, l = tid & 63;
    const int lr = l & 15, q8 = (l >> 4) * 8;

    const u16* ap  = ap0 + (size_t)(w * 16 + lr) * NS + q8;
    const u16* bp0 = bT0 + (size_t)lr * NS + q8;

    f32x4 acc[4];
    const f32x4 zero = {0.f, 0.f, 0.f, 0.f};
    #pragma unroll
    for (int nt = 0; nt < 4; ++nt) acc[nt] = zero;

    #pragma unroll 4
    for (int ks = 0; ks < 16; ++ks) {
        const bf16x8 a = *(const bf16x8*)(ap + ks * 32);
        #pragma unroll
        for (int nt = 0; nt < 4; ++nt) {
            const bf16x8 bfr = *(const bf16x8*)(bp0 + (size_t)nt * 16 * NS + ks * 32);
            acc[nt] = __builtin_amdgcn_mfma_f32_16x16x32_bf16(a, bfr, acc[nt], 0, 0, 0);
        }
    }

    const int rr = (l >> 4) * 4;
    #pragma unroll
    for (int nt = 0; nt < 4; ++nt)       // lds[o][i] = f2bf(G_m[o][i])
        #pragma unroll
        for (int rk = 0; rk < 4; ++rk)
            lds[(nt * 16 + lr) * 72 + (w * 16 + rr + rk)] = f2bf(acc[nt][rk]);
    __syncthreads();

    const int f = tid >> 6;              // 0..3
    #pragma unroll
    for (int f2 = 0; f2 < 8; f2 += 4) {  // fragments f and f+4
        const int fi = f2 + f;
        const int ks = fi >> 2, nt = fi & 3;
        const int o  = nt * 16 + (l & 15);
        const int i0 = ks * 32 + (l >> 4) * 8;
        u16 v[8];
        #pragma unroll
        for (int j = 0; j < 8; ++j) {
            u16 gv = lds[o * 72 + i0 + j];
            if (m == 0) gv = f2bf(bf2f(gv) + D[o * 64 + i0 + j]);
            v[j] = gv;
        }
        ushort4 p0; p0.x = v[0]; p0.y = v[1]; p0.z = v[2]; p0.w = v[3];
        ushort4 p1; p1.x = v[4]; p1.y = v[5]; p1.z = v[6]; p1.w = v[7];
        u16* dst = Gsw + ((size_t)(m * 8 + fi) * 64 + l) * 8;
        *(ushort4*)(dst + 0) = p0;
        *(ushort4*)(dst + 4) = p1;
    }
}

// ---------------------------------------------------------------------------
// conv_kernel v2 (round 12): lag-split waves.
// y[b,t,o] = sum_{m<96} sum_i G_m[o][i] x_bf[t-m][i].
// r10's row-split version was LDS-issue-bound: ~96 ds_read_b128/CU/lag
// (every wave re-read the same G through LDS) vs 155cy MFMA. Now wave w
// owns lags [24w,24w+24) and computes a PARTIAL for the FULL 128x64 tile
// (acc[8][4]): per wave-lag = 64 MFMA : 16 LDS X-reads : 8 L2 G-loads,
// no Gs buffer, no syncthreads in the main loop. Epilogue: 2-buffer LDS
// reduction (w0,w1 dump; w2,w3 add; all waves sum + store y).
// LDS 67,584 B -> 2 blocks/CU (8 waves/CU). Association changes
// (lag-grouped partials) -> absmax drifts slightly (accept <= ~0.12).
// ---------------------------------------------------------------------------
__global__ __launch_bounds__(256, 2) void conv_kernel(const float* __restrict__ x,
                                                      const u16* __restrict__ gsw,
                                                      float* __restrict__ y)
{
    // smem: [0, 33792)   Xs (u16, 32,112 B used) -> buf0 (f32 [128][66]) in epilogue
    //       [33792,67584) buf1 (f32 [128][66])
    __shared__ __align__(16) char smem[67584];
    u16*   Xs   = (u16*)smem;
    float* buf0 = (float*)smem;
    float* buf1 = (float*)(smem + 33792);

    const int tid = threadIdx.x;
    const int b  = blockIdx.y;
    const int t0 = blockIdx.x * CTILE;

    // Stage rows r = 0..222 -> time t = t0 + r - 95 (zero-fill t < 0),
    // fp32 -> bf16 in-flight (r7/r10-verified).
    {
        const int g = tid & 15;
        int r = tid >> 4;                    // 0..15
        #pragma unroll
        for (int it = 0; it < 14; ++it, r += 16) {
            if (r < XROWS) {
                const int t = t0 + r - (TLAG - 1);
                ushort4 o;
                if (t < 0) {
                    o.x = 0; o.y = 0; o.z = 0; o.w = 0;
                } else {
                    const float4 v = *(const float4*)(x + ((size_t)b * SEQ + t) * 64 + g * 4);
                    o.x = f2bf(v.x); o.y = f2bf(v.y); o.z = f2bf(v.z); o.w = f2bf(v.w);
                }
                *(ushort4*)&Xs[r * XSTR + g * 4] = o;
            }
        }
    }
    __syncthreads();

    const int w  = tid >> 6;      // wave 0..3 owns lags [24w, 24w+24)
    const int l  = tid & 63;
    const int lr = l & 15;
    const int q8 = (l >> 4) * 8;

    f32x4 acc[8][4];
    const f32x4 zero = {0.f, 0.f, 0.f, 0.f};
    #pragma unroll
    for (int mt = 0; mt < 8; ++mt)
        #pragma unroll
        for (int nt = 0; nt < 4; ++nt) acc[mt][nt] = zero;

    const uint4* gp4 = (const uint4*)gsw;

    for (int i = 0; i < TLAG / 4; ++i) {          // 24 lags per wave
        const int m = w * (TLAG / 4) + i;

        bf16x8 bc[8];                              // this lag's G fragments (L2-hot)
        #pragma unroll
        for (int f = 0; f < 8; ++f)
            bc[f] = __builtin_bit_cast(bf16x8, gp4[(size_t)m * 512 + f * 64 + l]);

        const int rbase = lr + (TLAG - 1) - m;
        #pragma unroll
        for (int mt = 0; mt < 8; ++mt) {
            const bf16x8 a0 = *(const bf16x8*)&Xs[(rbase + mt * 16) * XSTR + q8];
            const bf16x8 a1 = *(const bf16x8*)&Xs[(rbase + mt * 16) * XSTR + 32 + q8];
            #pragma unroll
            for (int nt = 0; nt < 4; ++nt)
                acc[mt][nt] = __builtin_amdgcn_mfma_f32_16x16x32_bf16(a0, bc[nt], acc[mt][nt], 0, 0, 0);
            #pragma unroll
            for (int nt = 0; nt < 4; ++nt)
                acc[mt][nt] = __builtin_amdgcn_mfma_f32_16x16x32_bf16(a1, bc[4 + nt], acc[mt][nt], 0, 0, 0);
        }
    }
    __syncthreads();   // Xs dead; smem becomes reduce buffers

    // ---- cross-wave reduction: y = (w0+w2) + (w1+w3) ----
    const int rr = (l >> 4) * 4;   // C/D: row = (lane>>4)*4+reg, col = lane&15
    if (w < 2) {
        float* bf = w ? buf1 : buf0;
        #pragma unroll
        for (int mt = 0; mt < 8; ++mt)
            #pragma unroll
            for (int nt = 0; nt < 4; ++nt)
                #pragma unroll
                for (int r = 0; r < 4; ++r)
                    bf[(mt * 16 + rr + r) * RSTR + nt * 16 + lr] = acc[mt][nt][r];
    }
    __syncthreads();
    if (w >= 2) {
        float* bf = (w == 2) ? buf0 : buf1;
        #pragma unroll
        for (int mt = 0; mt < 8; ++mt)
            #pragma unroll
            for (int nt = 0; nt < 4; ++nt)
                #pragma unroll
                for (int r = 0; r < 4; ++r)
                    bf[(mt * 16 + rr + r) * RSTR + nt * 16 + lr] += acc[mt][nt][r];
    }
    __syncthreads();
    // final: wave w stores rows [32w, 32w+32), lane l -> col l (coalesced 256B)
    {
        float* yp = y + ((size_t)b * SEQ + t0 + 32 * w) * 64 + l;
        #pragma unroll 4
        for (int i = 0; i < 32; ++i) {
            const int row = 32 * w + i;
            yp[(size_t)i * 64] = buf0[row * RSTR + l] + buf1[row * RSTR + l];
        }
    }
}

// ---------------------------------------------------------------------------
// Workspace layout (bytes, 16-aligned) — r10 offsets kept:
//   8,650,752   Arm .. 14,942,208 A64rm   (13 x 512KB power buffers)
//  15,532,032   L       1,048,576   (L_r = C A^r, r<16)
//  16,580,608   Rt        524,288   (R_q^T, q<6 used)
//  17,104,896   Gsw       786,432   (96-lag B-fragment-swizzled conv kernels)
//  total: 17,891,328
// ---------------------------------------------------------------------------
extern "C" void kernel_launch(void* const* d_in, const int* in_sizes, int n_in,
                              void* d_out, int out_size, void* d_ws, size_t ws_size,
                              hipStream_t stream)
{
    const float* x = (const float*)d_in[0];
    const float* A = (const float*)d_in[1];
    const float* B = (const float*)d_in[2];
    const float* C = (const float*)d_in[3];
    const float* D = (const float*)d_in[4];
    float* y = (float*)d_out;

    char* w = (char*)d_ws;
    u16* Arm   = (u16*)(w + 8650752);
    u16* At    = (u16*)(w + 9175040);
    u16* A2rm  = (u16*)(w + 9699328);
    u16* A2t   = (u16*)(w + 10223616);
    u16* A4rm  = (u16*)(w + 10747904);
    u16* A4t   = (u16*)(w + 11272192);
    u16* A8rm  = (u16*)(w + 11796480);
    u16* A8t   = (u16*)(w + 12320768);
    u16* A16rm = (u16*)(w + 12845056);
    u16* A16t  = (u16*)(w + 13369344);
    u16* A32rm = (u16*)(w + 13893632);
    u16* A32t  = (u16*)(w + 14417920);
    u16* A64rm = (u16*)(w + 14942208);
    u16* L     = (u16*)(w + 15532032);
    u16* Rt    = (u16*)(w + 16580608);
    u16* Gsw   = (u16*)(w + 17104896);

    prep_mat<<<1280, 256, 0, stream>>>(A, B, C, Arm, At, Rt, L);

    // Stage 1: L[1] = L[0]*A           ; A2  = A*A        (8 + 64 blocks)
    stage_kernel<<<72, 256, 0, stream>>>(L, At, L + 1 * BLK,
                                         Arm, At, A2rm, A2t, 8);
    // Stage 2: L[2+j] = L[j]*A2, j<2   ; A4  = A2*A2      (16 + 64)
    stage_kernel<<<80, 256, 0, stream>>>(L, A2t, L + 2 * BLK,
                                         A2rm, A2t, A4rm, A4t, 16);
    // Stage 3: L[4+j] = L[j]*A4, j<4   ; A8  = A4*A4      (32 + 64)
    stage_kernel<<<96, 256, 0, stream>>>(L, A4t, L + 4 * BLK,
                                         A4rm, A4t, A8rm, A8t, 32);
    // Stage 4: L[8+j] = L[j]*A8, j<8   ; A16 = A8*A8      (64 + 64)
    stage_kernel<<<128, 256, 0, stream>>>(L, A8t, L + 8 * BLK,
                                          A8rm, A8t, A16rm, A16t, 64);
    // Stage 5: R[1]^T = R[0]^T*A16^T   ; A32 = A16*A16    (8 + 64)
    stage_kernel<<<72, 256, 0, stream>>>(Rt, A16rm, Rt + 1 * BLK,
                                         A16rm, A16t, A32rm, A32t, 8);
    // Stage 6: R[2+j]^T = R[j]^T*A32^T ; A64 = A32*A32 (RM only) (16 + 64)
    stage_kernel<<<80, 256, 0, stream>>>(Rt, A32rm, Rt + 2 * BLK,
                                         A32rm, A32t, A64rm, nullptr, 16);
    // Stage 7: R[4+j]^T = R[j]^T*A64^T, j<2 (q = 4,5 at TLAG=96) (16)
    stage_kernel<<<16, 256, 0, stream>>>(Rt, A64rm, Rt + 4 * BLK,
                                         nullptr, nullptr, nullptr, nullptr, 16);
    // Stage 8: G_m = L_r R_q, swizzled + D fold            (96)
    g_kernel<<<TLAG, 256, 0, stream>>>(Rt, L, D, Gsw);

    conv_kernel<<<dim3(SEQ / CTILE, BATCH), 256, 0, stream>>>(x, Gsw, y);
}